// Round 3
// baseline (7948.640 us; speedup 1.0000x reference)
//
#include <hip/hip_runtime.h>
#include <math.h>

// RewardGuidanceModel: 8-layer Mamba2 stack, B=4096, L=17, fully fused.
// One workgroup (256 thr) per batch element; all activations in LDS/regs.
// R6: spill-free 6-blocks/CU. Same 27136B LDS layout as R5 (stride-18 rows,
// BC2/DTT/AT fully overlaid inside G2, RS folded, silu(z) parked in d_out).
// KEY FIX vs R5: the zv[17] reload is issued AFTER barrier (d), not before.
// The backend's register budget is LDS-occupancy-derived (~84 at 6 blk/CU);
// zv-before-barrier overlapped the scan's ~84-reg peak (hst[32]+xst[17]+
// pipelined B/C loads) -> spill cascade (R4: 40 VGPR/39GB, R5: 64 VGPR/9GB).
// After the move, scan peak == R3's proven 84-reg footprint -> no spill.

#define BATCH 4096
#define LSEQ 17
#define DM 128
#define DIN 324
#define DINNER 256
#define DSTATE 32
#define NH 32
#define NL 8
#define DPROJ 608
#define EPSF 1e-5f

#define OFF_WT 0
#define SZ_WT (NL * DM * DPROJ)
#define OFF_OWT (OFF_WT + SZ_WT)
#define SZ_OWT (NL * DINNER * DM)
#define OFF_IWT (OFF_OWT + SZ_OWT)
#define SZ_IWT (DIN * 64)
#define OFF_OUTWT (OFF_IWT + SZ_IWT)
#define SZ_OUTWT (DM * DIN)
#define WS_TOTAL (OFF_OUTWT + SZ_OUTWT)

// LDS layout (floats). Region [2176, 6784) is time-shared:
//   phases 1-2: XN  (128 rows x stride 18 = 2304)   [2176, 4480)
//   phases 3-4: BC2 (17*64=1088) DTT(544) AT(544)   [4480, 6656)
//   phases 5-7: G2  (256 rows x stride 18 = 4608)   [2176, 6784)
// Barrier (d) between scan reads and G2 writes makes the overlay safe.
#define XMAT 0
#define XN   2176
#define G2   2176
#define BC2  4480
#define DTT  5568
#define AT   6112
#define STG  0
#define SMEM_TOT 6784

__device__ __forceinline__ float siluf(float x) { return x / (1.f + __expf(-x)); }

__global__ void prep_weights(const float* __restrict__ in_proj_w,
                             const float* __restrict__ out_proj_w,
                             const float* __restrict__ mixer_norm_w,
                             const float* __restrict__ input_w,
                             const float* __restrict__ output_w,
                             float* __restrict__ ws) {
    int idx = blockIdx.x * 256 + threadIdx.x;
    if (idx < SZ_WT) {
        int l = idx / (DM * DPROJ);
        int r = idx - l * (DM * DPROJ);
        int d = r / DPROJ, j = r - d * DPROJ;
        ws[OFF_WT + idx] = in_proj_w[(l * DPROJ + j) * DM + d];
    } else if (idx < OFF_IWT) {
        int r2 = idx - OFF_OWT;
        int l = r2 / (DINNER * DM);
        int r = r2 - l * (DINNER * DM);
        int in_ = r / DM, o = r - in_ * DM;
        ws[idx] = out_proj_w[(l * DM + o) * DINNER + in_] * mixer_norm_w[l * DINNER + in_];
    } else if (idx < OFF_OUTWT) {
        int r = idx - OFF_IWT;
        int d = r / 64, o = r - d * 64;
        ws[idx] = input_w[o * DIN + d];
    } else if (idx < WS_TOTAL) {
        int r = idx - OFF_OUTWT;
        int d = r / DIN, o = r - d * DIN;
        ws[idx] = output_w[o * DM + d];
    }
}

__global__ __launch_bounds__(256, 4)
void mamba_all(const float* __restrict__ ini, const float* __restrict__ fut,
               const float* __restrict__ tflag, const float* __restrict__ sval,
               const float* __restrict__ input_b, const float* __restrict__ states_emb,
               const float* __restrict__ time_w, const float* __restrict__ time_b,
               const float* __restrict__ short_w, const float* __restrict__ short_b,
               const float* __restrict__ conv_w, const float* __restrict__ conv_b,
               const float* __restrict__ dt_bias, const float* __restrict__ A_log,
               const float* __restrict__ D_skip, const float* __restrict__ layer_norm_w,
               const float* __restrict__ output_b, const float* __restrict__ ws,
               float* __restrict__ out) {
    __shared__ float S[SMEM_TOT];
    const int tid = threadIdx.x;
    const int b = blockIdx.x;
    const int lane = tid & 63;
    const int wid = tid >> 6;

    const float tf = tflag[b];
    const float sv = sval[b];

    // per-block z-scratch inside d_out (4352 of 5184 floats; epilogue overwrites)
    float* zbuf = out + (size_t)b * (16 * DIN);

    // ---------- prologue: stage raw inputs ----------
    {
        const float* ir = ini + (size_t)b * DIN;
        const float* fr = fut + (size_t)b * 16 * DIN;
        for (int i = tid; i < DIN; i += 256) S[STG + i] = ir[i];
        for (int i = tid; i < 16 * DIN; i += 256) S[STG + DIN + i] = fr[i];
    }
    __syncthreads();
    // input projection (17x64); results in registers, written after barrier
    float ipacc[5]; float ipemb[5];
    int ipn = 0;
    {
        const float* iwT = ws + OFF_IWT;
        for (int idx = tid; idx < LSEQ * 64; idx += 256) {
            int t = idx >> 6, o = idx & 63;
            float acc = input_b[o];
            const float* sr = &S[STG + t * DIN];
            for (int d = 0; d < DIN; d += 4) {
                float4 sq = *reinterpret_cast<const float4*>(sr + d);
                acc = fmaf(sq.x, iwT[d * 64 + o], acc);
                acc = fmaf(sq.y, iwT[(d + 1) * 64 + o], acc);
                acc = fmaf(sq.z, iwT[(d + 2) * 64 + o], acc);
                acc = fmaf(sq.w, iwT[(d + 3) * 64 + o], acc);
            }
            ipacc[ipn] = acc;
            ipemb[ipn] = states_emb[t * 64 + o];
            ipn++;
        }
    }
    __syncthreads();
    {
        int k = 0;
        for (int idx = tid; idx < LSEQ * 64; idx += 256) {
            int t = idx >> 6, o = idx & 63;
            S[XMAT + t * DM + 64 + o] = ipacc[k];
            S[XMAT + t * DM + o] = ipemb[k];
            k++;
        }
    }
    __syncthreads();
    // te/se modulation (first halves)
    for (int idx = tid; idx < LSEQ * DM; idx += 256) {
        int d = idx & 127;
        float te0 = fmaf(tf, time_w[d], time_b[d]);
        float te1 = fmaf(tf, time_w[128 + d], time_b[128 + d]);
        float se0 = fmaf(sv, short_w[d], short_b[d]);
        float se1 = fmaf(sv, short_w[128 + d], short_b[128 + d]);
        S[XMAT + idx] = S[XMAT + idx] * te0 * se0 + te1 + se1;
    }

    const int h = tid >> 3;

    // ---------- 8 mamba2 layers ----------
    for (int l = 0; l < NL; ++l) {
        __syncthreads();   // (a) XMAT settled, prev-layer G2 reads done
        // phase 1: rmsnorm(x) -> XN [d][t] stride 18
        {
            const float* lnw = layer_norm_w + l * DM;
            for (int r = wid; r < LSEQ; r += 4) {
                float x0 = S[XMAT + r * DM + lane];
                float x1 = S[XMAT + r * DM + 64 + lane];
                float ss = x0 * x0 + x1 * x1;
                #pragma unroll
                for (int off = 1; off < 64; off <<= 1) ss += __shfl_xor(ss, off, 64);
                float rs = rsqrtf(ss * (1.f / 128.f) + EPSF);
                S[XN + lane * 18 + r] = x0 * rs * lnw[lane];
                S[XN + (64 + lane) * 18 + r] = x1 * rs * lnw[64 + lane];
            }
        }
        __syncthreads();   // (b)

        // phase 2, pass A: z (acc0) and xs (acc1) columns, all threads
        float acc0[17], acc1[17];
        #pragma unroll
        for (int t = 0; t < 17; ++t) { acc0[t] = 0.f; acc1[t] = 0.f; }
        {
            const float* wl = ws + OFF_WT + l * (DM * DPROJ);
            for (int d = 0; d < DM; ++d) {
                float w0 = wl[d * DPROJ + tid];
                float w1 = wl[d * DPROJ + 256 + tid];
                const float* xr = &S[XN + d * 18];
                float2 p0 = *reinterpret_cast<const float2*>(xr);
                float2 p1 = *reinterpret_cast<const float2*>(xr + 2);
                float2 p2 = *reinterpret_cast<const float2*>(xr + 4);
                float2 p3 = *reinterpret_cast<const float2*>(xr + 6);
                float2 p4 = *reinterpret_cast<const float2*>(xr + 8);
                float2 p5 = *reinterpret_cast<const float2*>(xr + 10);
                float2 p6 = *reinterpret_cast<const float2*>(xr + 12);
                float2 p7 = *reinterpret_cast<const float2*>(xr + 14);
                float x16 = xr[16];
                float xv[17] = {p0.x, p0.y, p1.x, p1.y, p2.x, p2.y, p3.x, p3.y,
                                p4.x, p4.y, p5.x, p5.y, p6.x, p6.y, p7.x, p7.y, x16};
                #pragma unroll
                for (int t = 0; t < 17; ++t) {
                    acc0[t] = fmaf(xv[t], w0, acc0[t]);
                    acc1[t] = fmaf(xv[t], w1, acc1[t]);
                }
            }
        }
        // park silu(z) in global scratch (frees acc0 before pass B/scan)
        {
            float* zb = zbuf + tid;
            #pragma unroll
            for (int t = 0; t < 17; ++t) zb[t * 256] = siluf(acc0[t]);
        }
        // phase 2, pass B: B/C/dt columns (acc2), waves 0-1 only
        float acc2[17];
        #pragma unroll
        for (int t = 0; t < 17; ++t) acc2[t] = 0.f;
        if (tid < 128) {
            const float* wl = ws + OFF_WT + l * (DM * DPROJ);
            const bool has2 = (tid < 96);
            for (int d = 0; d < DM; ++d) {
                float w2 = has2 ? wl[d * DPROJ + 512 + tid] : 0.f;
                const float* xr = &S[XN + d * 18];
                float2 p0 = *reinterpret_cast<const float2*>(xr);
                float2 p1 = *reinterpret_cast<const float2*>(xr + 2);
                float2 p2 = *reinterpret_cast<const float2*>(xr + 4);
                float2 p3 = *reinterpret_cast<const float2*>(xr + 6);
                float2 p4 = *reinterpret_cast<const float2*>(xr + 8);
                float2 p5 = *reinterpret_cast<const float2*>(xr + 10);
                float2 p6 = *reinterpret_cast<const float2*>(xr + 12);
                float2 p7 = *reinterpret_cast<const float2*>(xr + 14);
                float x16 = xr[16];
                float xv[17] = {p0.x, p0.y, p1.x, p1.y, p2.x, p2.y, p3.x, p3.y,
                                p4.x, p4.y, p5.x, p5.y, p6.x, p6.y, p7.x, p7.y, x16};
                #pragma unroll
                for (int t = 0; t < 17; ++t) acc2[t] = fmaf(xv[t], w2, acc2[t]);
            }
        }

        // phase 3: conv (register-local) + silu; xs stays in registers
        float xst[17];
        {
            const float* cw = conv_w + l * 320 * 4;
            const float* cb = conv_b + l * 320;
            {
                float k0 = cw[tid * 4 + 0], k1 = cw[tid * 4 + 1];
                float k2 = cw[tid * 4 + 2], k3 = cw[tid * 4 + 3];
                float bias = cb[tid];
                #pragma unroll
                for (int t = 0; t < 17; ++t) {
                    float s = fmaf(acc1[t], k3, bias);
                    if (t >= 1) s = fmaf(acc1[t - 1], k2, s);
                    if (t >= 2) s = fmaf(acc1[t - 2], k1, s);
                    if (t >= 3) s = fmaf(acc1[t - 3], k0, s);
                    xst[t] = siluf(s);
                }
            }
            if (tid < 64) {
                int c = 256 + tid;
                float k0 = cw[c * 4 + 0], k1 = cw[c * 4 + 1];
                float k2 = cw[c * 4 + 2], k3 = cw[c * 4 + 3];
                float bias = cb[c];
                #pragma unroll
                for (int t = 0; t < 17; ++t) {
                    float s = fmaf(acc2[t], k3, bias);
                    if (t >= 1) s = fmaf(acc2[t - 1], k2, s);
                    if (t >= 2) s = fmaf(acc2[t - 2], k1, s);
                    if (t >= 3) s = fmaf(acc2[t - 3], k0, s);
                    S[BC2 + t * 64 + tid] = siluf(s);
                }
            } else if (tid < 96) {
                int hh = tid - 64;
                float dtb = dt_bias[l * NH + hh];
                float eA = __expf(A_log[l * NH + hh]);
                #pragma unroll
                for (int t = 0; t < 17; ++t) {
                    float v = acc2[t] + dtb;
                    float dtv = (v > 15.f) ? v : log1pf(__expf(v));
                    S[DTT + hh * 17 + t] = dtv;
                    S[AT + hh * 17 + t] = __expf(-eA * dtv);
                }
            }
        }
        __syncthreads();   // (c)

        // phase 4: selective scan. thread = (h, p); state in regs; y overwrites xst
        {
            const float Dsk = D_skip[l * NH + h];
            float hst[32];
            #pragma unroll
            for (int n = 0; n < 32; ++n) hst[n] = 0.f;
            #pragma unroll
            for (int t = 0; t < 17; ++t) {
                float xs_t = xst[t];
                float dtv = S[DTT + h * 17 + t];
                float at = S[AT + h * 17 + t];
                float xd = xs_t * dtv;
                float y = 0.f;
                const float4* bq = reinterpret_cast<const float4*>(&S[BC2 + t * 64]);
                #pragma unroll
                for (int n4 = 0; n4 < 8; ++n4) {
                    float4 bb = bq[n4];
                    float4 cc = bq[8 + n4];
                    hst[4*n4+0] = fmaf(at, hst[4*n4+0], xd * bb.x); y = fmaf(hst[4*n4+0], cc.x, y);
                    hst[4*n4+1] = fmaf(at, hst[4*n4+1], xd * bb.y); y = fmaf(hst[4*n4+1], cc.y, y);
                    hst[4*n4+2] = fmaf(at, hst[4*n4+2], xd * bb.z); y = fmaf(hst[4*n4+2], cc.z, y);
                    hst[4*n4+3] = fmaf(at, hst[4*n4+3], xd * bb.w); y = fmaf(hst[4*n4+3], cc.w, y);
                }
                xst[t] = fmaf(xs_t, Dsk, y);
            }
        }
        __syncthreads();   // (d) all scan reads of BC2/DTT/AT done -> G2 may overwrite
        // reload silu(z) AFTER the barrier: keeps it out of the scan's peak
        // live set (the R4/R5 spill cause). L2-resident, 17 independent loads.
        float zv[17];
        {
            const float* zb = zbuf + tid;
            #pragma unroll
            for (int t = 0; t < 17; ++t) zv[t] = zb[t * 256];
        }
        // phase 5: G2 = silu(z) * y   (row tid, stride 18)
        #pragma unroll
        for (int t = 0; t < 17; ++t) {
            S[G2 + tid * 18 + t] = zv[t] * xst[t];
        }
        __syncthreads();   // (e)
        // phase 6: per-row sumsq -> scale G2 in place (folds RS away)
        for (int r = wid; r < LSEQ; r += 4) {
            float g0 = S[G2 + lane * 18 + r];
            float g1 = S[G2 + (64 + lane) * 18 + r];
            float g2v = S[G2 + (128 + lane) * 18 + r];
            float g3 = S[G2 + (192 + lane) * 18 + r];
            float ss = g0 * g0 + g1 * g1 + g2v * g2v + g3 * g3;
            #pragma unroll
            for (int off = 1; off < 64; off <<= 1) ss += __shfl_xor(ss, off, 64);
            float rs = rsqrtf(ss * (1.f / 256.f) + EPSF);
            S[G2 + lane * 18 + r] = g0 * rs;
            S[G2 + (64 + lane) * 18 + r] = g1 * rs;
            S[G2 + (128 + lane) * 18 + r] = g2v * rs;
            S[G2 + (192 + lane) * 18 + r] = g3 * rs;
        }
        __syncthreads();   // (f)
        // phase 7: out_proj + residual
        {
            const int o = tid & 127;
            const int half = tid >> 7;
            const int t0 = half ? 8 : 0;
            float acc[9];
            #pragma unroll
            for (int k = 0; k < 9; ++k) acc[k] = 0.f;
            const float* ow = ws + OFF_OWT + l * (DINNER * DM);
            for (int in = 0; in < DINNER; ++in) {
                float w = ow[in * DM + o];
                const float* gr = &S[G2 + in * 18 + t0];
                float2 g0 = *reinterpret_cast<const float2*>(gr);
                float2 g1 = *reinterpret_cast<const float2*>(gr + 2);
                float2 g2v = *reinterpret_cast<const float2*>(gr + 4);
                float2 g3 = *reinterpret_cast<const float2*>(gr + 6);
                acc[0] = fmaf(g0.x, w, acc[0]); acc[1] = fmaf(g0.y, w, acc[1]);
                acc[2] = fmaf(g1.x, w, acc[2]); acc[3] = fmaf(g1.y, w, acc[3]);
                acc[4] = fmaf(g2v.x, w, acc[4]); acc[5] = fmaf(g2v.y, w, acc[5]);
                acc[6] = fmaf(g3.x, w, acc[6]); acc[7] = fmaf(g3.y, w, acc[7]);
                if (half) acc[8] = fmaf(gr[8], w, acc[8]);
            }
            const int nt = half ? 9 : 8;
            for (int k = 0; k < nt; ++k) {
                int t = t0 + k;
                S[XMAT + t * DM + o] += acc[k];
            }
        }
    }

    // ---------- epilogue ----------
    __syncthreads();
    for (int idx = tid; idx < LSEQ * DM; idx += 256) {
        int d = idx & 127;
        float te2 = fmaf(tf, time_w[256 + d], time_b[256 + d]);
        float te3 = fmaf(tf, time_w[384 + d], time_b[384 + d]);
        float se2 = fmaf(sv, short_w[256 + d], short_b[256 + d]);
        float se3 = fmaf(sv, short_w[384 + d], short_b[384 + d]);
        S[XN + idx] = S[XMAT + idx] * te2 * se2 + te3 + se3;
    }
    __syncthreads();
    {
        const float* outwT = ws + OFF_OUTWT;
        float* orow = out + (size_t)b * 16 * DIN;
        for (int idx = tid; idx < 16 * DIN; idx += 256) {
            int t1 = idx / DIN;
            int o = idx - t1 * DIN;
            float acc = output_b[o];
            const float* xr = &S[XN + (t1 + 1) * DM];
            for (int d = 0; d < DM; d += 4) {
                float4 xq = *reinterpret_cast<const float4*>(xr + d);
                acc = fmaf(xq.x, outwT[d * DIN + o], acc);
                acc = fmaf(xq.y, outwT[(d + 1) * DIN + o], acc);
                acc = fmaf(xq.z, outwT[(d + 2) * DIN + o], acc);
                acc = fmaf(xq.w, outwT[(d + 3) * DIN + o], acc);
            }
            orow[idx] = acc;
        }
    }
}

extern "C" void kernel_launch(void* const* d_in, const int* in_sizes, int n_in,
                              void* d_out, int out_size, void* d_ws, size_t ws_size,
                              hipStream_t stream) {
    (void)in_sizes; (void)n_in; (void)out_size; (void)ws_size;
    const float* init_states    = (const float*)d_in[0];
    const float* future_states  = (const float*)d_in[1];
    const float* time_flags     = (const float*)d_in[2];
    const float* shortcut_value = (const float*)d_in[3];
    const float* input_w        = (const float*)d_in[4];
    const float* input_b        = (const float*)d_in[5];
    const float* states_emb     = (const float*)d_in[6];
    const float* time_w         = (const float*)d_in[7];
    const float* time_b         = (const float*)d_in[8];
    const float* short_w        = (const float*)d_in[9];
    const float* short_b        = (const float*)d_in[10];
    const float* in_proj_w      = (const float*)d_in[11];
    const float* conv_w         = (const float*)d_in[12];
    const float* conv_b         = (const float*)d_in[13];
    const float* dt_bias        = (const float*)d_in[14];
    const float* A_log          = (const float*)d_in[15];
    const float* D_skip         = (const float*)d_in[16];
    const float* mixer_norm_w   = (const float*)d_in[17];
    const float* out_proj_w     = (const float*)d_in[18];
    const float* layer_norm_w   = (const float*)d_in[19];
    const float* output_w       = (const float*)d_in[20];
    const float* output_b       = (const float*)d_in[21];
    float* ws = (float*)d_ws;
    float* outp = (float*)d_out;

    prep_weights<<<(WS_TOTAL + 255) / 256, 256, 0, stream>>>(
        in_proj_w, out_proj_w, mixer_norm_w, input_w, output_w, ws);
    mamba_all<<<BATCH, 256, 0, stream>>>(
        init_states, future_states, time_flags, shortcut_value,
        input_b, states_emb, time_w, time_b, short_w, short_b,
        conv_w, conv_b, dt_bias, A_log, D_skip, layer_norm_w,
        output_b, ws, outp);
}

// Round 4
// 7499.043 us; speedup vs baseline: 1.0600x; 1.0600x over previous
//
#include <hip/hip_runtime.h>
#include <math.h>

// RewardGuidanceModel: 8-layer Mamba2 stack, B=4096, L=17, fully fused.
// One workgroup (256 thr) per batch element; all activations in LDS/regs.
// R7: true 64-VGPR fit. Empirical hipcc mapping: launch_bounds(256,n) caps
// VGPR at ~256/n (3->84, 4->64, 6->40); HW wave allocation halves at the
// 64-VGPR boundary, so 84 VGPR = 16 waves/CU (LDS compaction wasted) and
// 64-with-spills = 6 GB scratch (R5/R6). This version diets the peak live
// set below 64 so (256,4) is spill-free at 6 blocks/CU (24 waves):
//  - scan split into 2x16-state passes (hst[16]+y17[17] vs hst[32])
//  - conv computed in place into acc1 (descending t) - frees 17 regs
//  - no xv[17]/zv[17] temp arrays (direct float2 consumption; z reload
//    fused into the G2 store)
// LDS layout (27136 B) and barrier structure identical to R6.

#define BATCH 4096
#define LSEQ 17
#define DM 128
#define DIN 324
#define DINNER 256
#define DSTATE 32
#define NH 32
#define NL 8
#define DPROJ 608
#define EPSF 1e-5f

#define OFF_WT 0
#define SZ_WT (NL * DM * DPROJ)
#define OFF_OWT (OFF_WT + SZ_WT)
#define SZ_OWT (NL * DINNER * DM)
#define OFF_IWT (OFF_OWT + SZ_OWT)
#define SZ_IWT (DIN * 64)
#define OFF_OUTWT (OFF_IWT + SZ_IWT)
#define SZ_OUTWT (DM * DIN)
#define WS_TOTAL (OFF_OUTWT + SZ_OUTWT)

// LDS layout (floats). Region [2176, 6784) is time-shared:
//   phases 1-2: XN  (128 rows x stride 18 = 2304)   [2176, 4480)
//   phases 3-4: BC2 (17*64=1088) DTT(544) AT(544)   [4480, 6656)
//   phases 5-7: G2  (256 rows x stride 18 = 4608)   [2176, 6784)
// Barrier (d) between scan reads and G2 writes makes the overlay safe.
#define XMAT 0
#define XN   2176
#define G2   2176
#define BC2  4480
#define DTT  5568
#define AT   6112
#define STG  0
#define SMEM_TOT 6784

__device__ __forceinline__ float siluf(float x) { return x / (1.f + __expf(-x)); }

__global__ void prep_weights(const float* __restrict__ in_proj_w,
                             const float* __restrict__ out_proj_w,
                             const float* __restrict__ mixer_norm_w,
                             const float* __restrict__ input_w,
                             const float* __restrict__ output_w,
                             float* __restrict__ ws) {
    int idx = blockIdx.x * 256 + threadIdx.x;
    if (idx < SZ_WT) {
        int l = idx / (DM * DPROJ);
        int r = idx - l * (DM * DPROJ);
        int d = r / DPROJ, j = r - d * DPROJ;
        ws[OFF_WT + idx] = in_proj_w[(l * DPROJ + j) * DM + d];
    } else if (idx < OFF_IWT) {
        int r2 = idx - OFF_OWT;
        int l = r2 / (DINNER * DM);
        int r = r2 - l * (DINNER * DM);
        int in_ = r / DM, o = r - in_ * DM;
        ws[idx] = out_proj_w[(l * DM + o) * DINNER + in_] * mixer_norm_w[l * DINNER + in_];
    } else if (idx < OFF_OUTWT) {
        int r = idx - OFF_IWT;
        int d = r / 64, o = r - d * 64;
        ws[idx] = input_w[o * DIN + d];
    } else if (idx < WS_TOTAL) {
        int r = idx - OFF_OUTWT;
        int d = r / DIN, o = r - d * DIN;
        ws[idx] = output_w[o * DM + d];
    }
}

__global__ __launch_bounds__(256, 4)
void mamba_all(const float* __restrict__ ini, const float* __restrict__ fut,
               const float* __restrict__ tflag, const float* __restrict__ sval,
               const float* __restrict__ input_b, const float* __restrict__ states_emb,
               const float* __restrict__ time_w, const float* __restrict__ time_b,
               const float* __restrict__ short_w, const float* __restrict__ short_b,
               const float* __restrict__ conv_w, const float* __restrict__ conv_b,
               const float* __restrict__ dt_bias, const float* __restrict__ A_log,
               const float* __restrict__ D_skip, const float* __restrict__ layer_norm_w,
               const float* __restrict__ output_b, const float* __restrict__ ws,
               float* __restrict__ out) {
    __shared__ float S[SMEM_TOT];
    const int tid = threadIdx.x;
    const int b = blockIdx.x;
    const int lane = tid & 63;
    const int wid = tid >> 6;

    const float tf = tflag[b];
    const float sv = sval[b];

    // per-block z-scratch inside d_out (4352 of 5184 floats; epilogue overwrites)
    float* zbuf = out + (size_t)b * (16 * DIN);

    // ---------- prologue: stage raw inputs ----------
    {
        const float* ir = ini + (size_t)b * DIN;
        const float* fr = fut + (size_t)b * 16 * DIN;
        for (int i = tid; i < DIN; i += 256) S[STG + i] = ir[i];
        for (int i = tid; i < 16 * DIN; i += 256) S[STG + DIN + i] = fr[i];
    }
    __syncthreads();
    // input projection (17x64); results in registers, written after barrier
    float ipacc[5]; float ipemb[5];
    int ipn = 0;
    {
        const float* iwT = ws + OFF_IWT;
        for (int idx = tid; idx < LSEQ * 64; idx += 256) {
            int t = idx >> 6, o = idx & 63;
            float acc = input_b[o];
            const float* sr = &S[STG + t * DIN];
            for (int d = 0; d < DIN; d += 4) {
                float4 sq = *reinterpret_cast<const float4*>(sr + d);
                acc = fmaf(sq.x, iwT[d * 64 + o], acc);
                acc = fmaf(sq.y, iwT[(d + 1) * 64 + o], acc);
                acc = fmaf(sq.z, iwT[(d + 2) * 64 + o], acc);
                acc = fmaf(sq.w, iwT[(d + 3) * 64 + o], acc);
            }
            ipacc[ipn] = acc;
            ipemb[ipn] = states_emb[t * 64 + o];
            ipn++;
        }
    }
    __syncthreads();
    {
        int k = 0;
        for (int idx = tid; idx < LSEQ * 64; idx += 256) {
            int t = idx >> 6, o = idx & 63;
            S[XMAT + t * DM + 64 + o] = ipacc[k];
            S[XMAT + t * DM + o] = ipemb[k];
            k++;
        }
    }
    __syncthreads();
    // te/se modulation (first halves)
    for (int idx = tid; idx < LSEQ * DM; idx += 256) {
        int d = idx & 127;
        float te0 = fmaf(tf, time_w[d], time_b[d]);
        float te1 = fmaf(tf, time_w[128 + d], time_b[128 + d]);
        float se0 = fmaf(sv, short_w[d], short_b[d]);
        float se1 = fmaf(sv, short_w[128 + d], short_b[128 + d]);
        S[XMAT + idx] = S[XMAT + idx] * te0 * se0 + te1 + se1;
    }

    const int h = tid >> 3;

    // ---------- 8 mamba2 layers ----------
    for (int l = 0; l < NL; ++l) {
        __syncthreads();   // (a) XMAT settled, prev-layer G2 reads done
        // phase 1: rmsnorm(x) -> XN [d][t] stride 18
        {
            const float* lnw = layer_norm_w + l * DM;
            for (int r = wid; r < LSEQ; r += 4) {
                float x0 = S[XMAT + r * DM + lane];
                float x1 = S[XMAT + r * DM + 64 + lane];
                float ss = x0 * x0 + x1 * x1;
                #pragma unroll
                for (int off = 1; off < 64; off <<= 1) ss += __shfl_xor(ss, off, 64);
                float rs = rsqrtf(ss * (1.f / 128.f) + EPSF);
                S[XN + lane * 18 + r] = x0 * rs * lnw[lane];
                S[XN + (64 + lane) * 18 + r] = x1 * rs * lnw[64 + lane];
            }
        }
        __syncthreads();   // (b)

        // phase 2, pass A: z (acc0) and xs (acc1) columns, all threads.
        // float2 LDS loads consumed directly (no xv[] temp array).
        float acc0[17], acc1[17];
        #pragma unroll
        for (int t = 0; t < 17; ++t) { acc0[t] = 0.f; acc1[t] = 0.f; }
        {
            const float* wl = ws + OFF_WT + l * (DM * DPROJ);
            for (int d = 0; d < DM; ++d) {
                float w0 = wl[d * DPROJ + tid];
                float w1 = wl[d * DPROJ + 256 + tid];
                const float* xr = &S[XN + d * 18];
                #pragma unroll
                for (int tt = 0; tt < 8; ++tt) {
                    float2 p = *reinterpret_cast<const float2*>(xr + 2 * tt);
                    acc0[2*tt]   = fmaf(p.x, w0, acc0[2*tt]);
                    acc1[2*tt]   = fmaf(p.x, w1, acc1[2*tt]);
                    acc0[2*tt+1] = fmaf(p.y, w0, acc0[2*tt+1]);
                    acc1[2*tt+1] = fmaf(p.y, w1, acc1[2*tt+1]);
                }
                float x16 = xr[16];
                acc0[16] = fmaf(x16, w0, acc0[16]);
                acc1[16] = fmaf(x16, w1, acc1[16]);
            }
        }
        // park silu(z) in global scratch (frees acc0 before pass B/scan)
        {
            float* zb = zbuf + tid;
            #pragma unroll
            for (int t = 0; t < 17; ++t) zb[t * 256] = siluf(acc0[t]);
        }
        // phase 2, pass B: B/C/dt columns (acc2), waves 0-1 only
        float acc2[17];
        #pragma unroll
        for (int t = 0; t < 17; ++t) acc2[t] = 0.f;
        if (tid < 128) {
            const float* wl = ws + OFF_WT + l * (DM * DPROJ);
            const bool has2 = (tid < 96);
            for (int d = 0; d < DM; ++d) {
                float w2 = has2 ? wl[d * DPROJ + 512 + tid] : 0.f;
                const float* xr = &S[XN + d * 18];
                #pragma unroll
                for (int tt = 0; tt < 8; ++tt) {
                    float2 p = *reinterpret_cast<const float2*>(xr + 2 * tt);
                    acc2[2*tt]   = fmaf(p.x, w2, acc2[2*tt]);
                    acc2[2*tt+1] = fmaf(p.y, w2, acc2[2*tt+1]);
                }
                acc2[16] = fmaf(xr[16], w2, acc2[16]);
            }
        }

        // phase 3: conv IN PLACE into acc1 (descending t: inputs t-3..t are
        // only overwritten at indices > t) -> acc1 becomes silu-conv'd xs.
        {
            const float* cw = conv_w + l * 320 * 4;
            const float* cb = conv_b + l * 320;
            {
                float k0 = cw[tid * 4 + 0], k1 = cw[tid * 4 + 1];
                float k2 = cw[tid * 4 + 2], k3 = cw[tid * 4 + 3];
                float bias = cb[tid];
                #pragma unroll
                for (int t = 16; t >= 0; --t) {
                    float s = fmaf(acc1[t], k3, bias);
                    if (t >= 1) s = fmaf(acc1[t - 1], k2, s);
                    if (t >= 2) s = fmaf(acc1[t - 2], k1, s);
                    if (t >= 3) s = fmaf(acc1[t - 3], k0, s);
                    acc1[t] = siluf(s);
                }
            }
            if (tid < 64) {
                int c = 256 + tid;
                float k0 = cw[c * 4 + 0], k1 = cw[c * 4 + 1];
                float k2 = cw[c * 4 + 2], k3 = cw[c * 4 + 3];
                float bias = cb[c];
                #pragma unroll
                for (int t = 0; t < 17; ++t) {
                    float s = fmaf(acc2[t], k3, bias);
                    if (t >= 1) s = fmaf(acc2[t - 1], k2, s);
                    if (t >= 2) s = fmaf(acc2[t - 2], k1, s);
                    if (t >= 3) s = fmaf(acc2[t - 3], k0, s);
                    S[BC2 + t * 64 + tid] = siluf(s);
                }
            } else if (tid < 96) {
                int hh = tid - 64;
                float dtb = dt_bias[l * NH + hh];
                float eA = __expf(A_log[l * NH + hh]);
                #pragma unroll
                for (int t = 0; t < 17; ++t) {
                    float v = acc2[t] + dtb;
                    float dtv = (v > 15.f) ? v : log1pf(__expf(v));
                    S[DTT + hh * 17 + t] = dtv;
                    S[AT + hh * 17 + t] = __expf(-eA * dtv);
                }
            }
        }
        __syncthreads();   // (c)

        // phase 4: selective scan, state dim split 16+16 to cap VGPR
        // pressure (hst[16]+acc1[17]+y17[17] ~ 50 live vs hst[32] ~ 63+).
        float y17[17];
        {
            float hst[16];
            #pragma unroll
            for (int n = 0; n < 16; ++n) hst[n] = 0.f;
            #pragma unroll
            for (int t = 0; t < 17; ++t) {
                float dtv = S[DTT + h * 17 + t];
                float at = S[AT + h * 17 + t];
                float xd = acc1[t] * dtv;
                float y = 0.f;
                const float4* bq = reinterpret_cast<const float4*>(&S[BC2 + t * 64]);
                #pragma unroll
                for (int q = 0; q < 4; ++q) {
                    float4 bb = bq[q];
                    hst[4*q+0] = fmaf(at, hst[4*q+0], xd * bb.x);
                    hst[4*q+1] = fmaf(at, hst[4*q+1], xd * bb.y);
                    hst[4*q+2] = fmaf(at, hst[4*q+2], xd * bb.z);
                    hst[4*q+3] = fmaf(at, hst[4*q+3], xd * bb.w);
                    float4 cc = bq[8 + q];
                    y = fmaf(hst[4*q+0], cc.x, y);
                    y = fmaf(hst[4*q+1], cc.y, y);
                    y = fmaf(hst[4*q+2], cc.z, y);
                    y = fmaf(hst[4*q+3], cc.w, y);
                }
                y17[t] = y;
            }
        }
        {
            float hst[16];
            #pragma unroll
            for (int n = 0; n < 16; ++n) hst[n] = 0.f;
            const float Dsk = D_skip[l * NH + h];
            #pragma unroll
            for (int t = 0; t < 17; ++t) {
                float dtv = S[DTT + h * 17 + t];
                float at = S[AT + h * 17 + t];
                float xd = acc1[t] * dtv;
                float y = y17[t];
                const float4* bq = reinterpret_cast<const float4*>(&S[BC2 + t * 64]);
                #pragma unroll
                for (int q = 4; q < 8; ++q) {
                    float4 bb = bq[q];
                    hst[4*(q-4)+0] = fmaf(at, hst[4*(q-4)+0], xd * bb.x);
                    hst[4*(q-4)+1] = fmaf(at, hst[4*(q-4)+1], xd * bb.y);
                    hst[4*(q-4)+2] = fmaf(at, hst[4*(q-4)+2], xd * bb.z);
                    hst[4*(q-4)+3] = fmaf(at, hst[4*(q-4)+3], xd * bb.w);
                    float4 cc = bq[8 + q];
                    y = fmaf(hst[4*(q-4)+0], cc.x, y);
                    y = fmaf(hst[4*(q-4)+1], cc.y, y);
                    y = fmaf(hst[4*(q-4)+2], cc.z, y);
                    y = fmaf(hst[4*(q-4)+3], cc.w, y);
                }
                y17[t] = fmaf(acc1[t], Dsk, y);
            }
        }
        __syncthreads();   // (d) all scan reads of BC2/DTT/AT done -> G2 may overwrite
        // phase 5: G2 = silu(z) * y ; z reload fused into the store (no zv[])
        {
            const float* zb = zbuf + tid;
            #pragma unroll
            for (int t = 0; t < 17; ++t) {
                S[G2 + tid * 18 + t] = zb[t * 256] * y17[t];
            }
        }
        __syncthreads();   // (e)
        // phase 6: per-row sumsq -> scale G2 in place (folds RS away)
        for (int r = wid; r < LSEQ; r += 4) {
            float g0 = S[G2 + lane * 18 + r];
            float g1 = S[G2 + (64 + lane) * 18 + r];
            float g2v = S[G2 + (128 + lane) * 18 + r];
            float g3 = S[G2 + (192 + lane) * 18 + r];
            float ss = g0 * g0 + g1 * g1 + g2v * g2v + g3 * g3;
            #pragma unroll
            for (int off = 1; off < 64; off <<= 1) ss += __shfl_xor(ss, off, 64);
            float rs = rsqrtf(ss * (1.f / 256.f) + EPSF);
            S[G2 + lane * 18 + r] = g0 * rs;
            S[G2 + (64 + lane) * 18 + r] = g1 * rs;
            S[G2 + (128 + lane) * 18 + r] = g2v * rs;
            S[G2 + (192 + lane) * 18 + r] = g3 * rs;
        }
        __syncthreads();   // (f)
        // phase 7: out_proj + residual
        {
            const int o = tid & 127;
            const int half = tid >> 7;
            const int t0 = half ? 8 : 0;
            float acc[9];
            #pragma unroll
            for (int k = 0; k < 9; ++k) acc[k] = 0.f;
            const float* ow = ws + OFF_OWT + l * (DINNER * DM);
            for (int in = 0; in < DINNER; ++in) {
                float w = ow[in * DM + o];
                const float* gr = &S[G2 + in * 18 + t0];
                float2 g0 = *reinterpret_cast<const float2*>(gr);
                float2 g1 = *reinterpret_cast<const float2*>(gr + 2);
                float2 g2v = *reinterpret_cast<const float2*>(gr + 4);
                float2 g3 = *reinterpret_cast<const float2*>(gr + 6);
                acc[0] = fmaf(g0.x, w, acc[0]); acc[1] = fmaf(g0.y, w, acc[1]);
                acc[2] = fmaf(g1.x, w, acc[2]); acc[3] = fmaf(g1.y, w, acc[3]);
                acc[4] = fmaf(g2v.x, w, acc[4]); acc[5] = fmaf(g2v.y, w, acc[5]);
                acc[6] = fmaf(g3.x, w, acc[6]); acc[7] = fmaf(g3.y, w, acc[7]);
                if (half) acc[8] = fmaf(gr[8], w, acc[8]);
            }
            const int nt = half ? 9 : 8;
            for (int k = 0; k < nt; ++k) {
                int t = t0 + k;
                S[XMAT + t * DM + o] += acc[k];
            }
        }
    }

    // ---------- epilogue ----------
    __syncthreads();
    for (int idx = tid; idx < LSEQ * DM; idx += 256) {
        int d = idx & 127;
        float te2 = fmaf(tf, time_w[256 + d], time_b[256 + d]);
        float te3 = fmaf(tf, time_w[384 + d], time_b[384 + d]);
        float se2 = fmaf(sv, short_w[256 + d], short_b[256 + d]);
        float se3 = fmaf(sv, short_w[384 + d], short_b[384 + d]);
        S[XN + idx] = S[XMAT + idx] * te2 * se2 + te3 + se3;
    }
    __syncthreads();
    {
        const float* outwT = ws + OFF_OUTWT;
        float* orow = out + (size_t)b * 16 * DIN;
        for (int idx = tid; idx < 16 * DIN; idx += 256) {
            int t1 = idx / DIN;
            int o = idx - t1 * DIN;
            float acc = output_b[o];
            const float* xr = &S[XN + (t1 + 1) * DM];
            for (int d = 0; d < DM; d += 4) {
                float4 xq = *reinterpret_cast<const float4*>(xr + d);
                acc = fmaf(xq.x, outwT[d * DIN + o], acc);
                acc = fmaf(xq.y, outwT[(d + 1) * DIN + o], acc);
                acc = fmaf(xq.z, outwT[(d + 2) * DIN + o], acc);
                acc = fmaf(xq.w, outwT[(d + 3) * DIN + o], acc);
            }
            orow[idx] = acc;
        }
    }
}

extern "C" void kernel_launch(void* const* d_in, const int* in_sizes, int n_in,
                              void* d_out, int out_size, void* d_ws, size_t ws_size,
                              hipStream_t stream) {
    (void)in_sizes; (void)n_in; (void)out_size; (void)ws_size;
    const float* init_states    = (const float*)d_in[0];
    const float* future_states  = (const float*)d_in[1];
    const float* time_flags     = (const float*)d_in[2];
    const float* shortcut_value = (const float*)d_in[3];
    const float* input_w        = (const float*)d_in[4];
    const float* input_b        = (const float*)d_in[5];
    const float* states_emb     = (const float*)d_in[6];
    const float* time_w         = (const float*)d_in[7];
    const float* time_b         = (const float*)d_in[8];
    const float* short_w        = (const float*)d_in[9];
    const float* short_b        = (const float*)d_in[10];
    const float* in_proj_w      = (const float*)d_in[11];
    const float* conv_w         = (const float*)d_in[12];
    const float* conv_b         = (const float*)d_in[13];
    const float* dt_bias        = (const float*)d_in[14];
    const float* A_log          = (const float*)d_in[15];
    const float* D_skip         = (const float*)d_in[16];
    const float* mixer_norm_w   = (const float*)d_in[17];
    const float* out_proj_w     = (const float*)d_in[18];
    const float* layer_norm_w   = (const float*)d_in[19];
    const float* output_w       = (const float*)d_in[20];
    const float* output_b       = (const float*)d_in[21];
    float* ws = (float*)d_ws;
    float* outp = (float*)d_out;

    prep_weights<<<(WS_TOTAL + 255) / 256, 256, 0, stream>>>(
        in_proj_w, out_proj_w, mixer_norm_w, input_w, output_w, ws);
    mamba_all<<<BATCH, 256, 0, stream>>>(
        init_states, future_states, time_flags, shortcut_value,
        input_b, states_emb, time_w, time_b, short_w, short_b,
        conv_w, conv_b, dt_bias, A_log, D_skip, layer_norm_w,
        output_b, ws, outp);
}